// Round 5
// baseline (704.451 us; speedup 1.0000x reference)
//
#include <hip/hip_runtime.h>

typedef _Float16 f16;
typedef _Float16 f16x8 __attribute__((ext_vector_type(8)));
typedef float f32x4 __attribute__((ext_vector_type(4)));

#define NN 8192
#define GG 128
#define NSPLIT 8

typedef __attribute__((address_space(3))) unsigned as3u;
typedef const __attribute__((address_space(1))) unsigned as1u;

__device__ __forceinline__ void gload16(const f16* g, f16* l) {
  __builtin_amdgcn_global_load_lds((as1u*)g, (as3u*)l, 16, 0, 0);
}

#define SBAR() asm volatile("s_barrier" ::: "memory")
#define WAITV(N) asm volatile("s_waitcnt vmcnt(" #N ")" ::: "memory")
#define WAITL0() asm volatile("s_waitcnt lgkmcnt(0)" ::: "memory")

__device__ __forceinline__ f16x8 ldcvt8(const float* p) {
  f32x4 a = *(const f32x4*)p;
  f32x4 b = *(const f32x4*)(p + 4);
  f16x8 r;
  r[0] = (f16)a[0]; r[1] = (f16)a[1]; r[2] = (f16)a[2]; r[3] = (f16)a[3];
  r[4] = (f16)b[0]; r[5] = (f16)b[1]; r[6] = (f16)b[2]; r[7] = (f16)b[3];
  return r;
}

// Device-wide barrier: all 512 blocks are co-resident by capacity (LDS 64KB ->
// 2 blocks/CU, launch_bounds(256,2), grid = 2x256). Monotonic counter, zeroed
// by a captured hipMemsetAsync each replay. Release: syncthreads drains vmcnt,
// threadfence writes back XCD L2, device-scope atomicAdd publishes. Acquire:
// agent-scope spin load, then threadfence invalidates stale lines.
__device__ __forceinline__ void gbar(unsigned* c, unsigned target) {
  __syncthreads();
  if (threadIdx.x == 0) {
    __threadfence();
    atomicAdd(c, 1u);
    while (__hip_atomic_load(c, __ATOMIC_RELAXED, __HIP_MEMORY_SCOPE_AGENT) < target)
      __builtin_amdgcn_s_sleep(32);
  }
  __syncthreads();
  __threadfence();
}

// ---------------- phase 0: wz[k] = W_k @ z0, k=0..3 (re-derived for 4 waves) ----
// block b: ktap = b>>7, n0 = (b&127)*64. Wave w: rows w*32..+32, all 64 n-cols.
// Fragment formulas identical to the proven k_wz (A rows rowA+lo/+16+lo, k=8hi+32s;
// B rows n0+16fn+lo; C row = rowA+16fm+4hi+rr, col = n0+16fn+lo).
__device__ __forceinline__ void ph_wz(int b, int tid, const float* __restrict__ wt,
                                      const float* __restrict__ x, f16* __restrict__ wz) {
  const int w = tid >> 6, l = tid & 63, lo = l & 15, hi = l >> 4;
  const int ktap = b >> 7;
  const int n0 = (b & 127) * 64;
  const int rowA = w * 32;
  const float* wA0 = wt + (size_t)(rowA + lo) * 512 + (size_t)ktap * 128 + 8 * hi;
  const float* wA1 = wA0 + (size_t)16 * 512;
  f32x4 acc[2][4] = {};
#pragma unroll
  for (int s = 0; s < 4; ++s) {
    f16x8 a0 = ldcvt8(wA0 + s * 32);
    f16x8 a1 = ldcvt8(wA1 + s * 32);
#pragma unroll
    for (int fn = 0; fn < 4; ++fn) {
      f16x8 bfr = ldcvt8(x + (size_t)(n0 + 16 * fn + lo) * GG + 8 * hi + s * 32);
      acc[0][fn] = __builtin_amdgcn_mfma_f32_16x16x32_f16(a0, bfr, acc[0][fn], 0, 0, 0);
      acc[1][fn] = __builtin_amdgcn_mfma_f32_16x16x32_f16(a1, bfr, acc[1][fn], 0, 0, 0);
    }
  }
  f16* out = wz + (size_t)ktap * (GG * NN);
#pragma unroll
  for (int fm = 0; fm < 2; ++fm)
#pragma unroll
    for (int fn = 0; fn < 4; ++fn)
#pragma unroll
      for (int rr = 0; rr < 4; ++rr) {
        const int row = rowA + 16 * fm + 4 * hi + rr;
        out[(size_t)row * NN + n0 + 16 * fn + lo] = (f16)acc[fm][fn][rr];
      }
}

// ---------------- phase 1: fused tap1 (proven R2 schedule, verbatim) ----------------
__device__ __forceinline__ void ph_tap1(int b, int tid, f16* sm, const f16* __restrict__ A,
                                        const float* __restrict__ S, f16* __restrict__ Sbt,
                                        f16* __restrict__ Part) {
  const int w = tid >> 6, l = tid & 63, lo = l & 15, hi = l >> 4;
  const int wm = w >> 1, wn = w & 1;
  const int kg = tid >> 5, cg = tid & 31, ch = kg >> 2, khi = kg & 3;
  const int nb = b & 63, ks = b >> 6;
  const int n0 = nb * 128;
  const int k0 = ks * 1024;

  const int r1 = tid >> 2, q = tid & 3;
  const f16* aS1 = A + (size_t)r1 * NN + k0 + 8 * (q ^ (r1 & 3));
  const f16* aS2 = A + (size_t)(64 + r1) * NN + k0 + 8 * (q ^ (r1 & 3));
  const float* Sb = S + (size_t)(k0 + 8 * kg) * NN + n0 + 4 * cg;
  f16* chunkBase = Sbt + (((size_t)ks * 64 + nb) * 32) * 4096;

  f32x4 rgA[8], rgB[8];
  f32x4 acc[4][4] = {};

#define ISSUE_R(T, RG)                                                          \
  do {                                                                          \
    const float* s_ = Sb + (size_t)(64 * (T)) * NN;                             \
    _Pragma("unroll") for (int j_ = 0; j_ < 8; ++j_)                            \
        RG[j_] = __builtin_nontemporal_load((const f32x4*)(s_ + (size_t)j_ * NN)); \
  } while (0)

#define ISSUE_G(T)                                                              \
  do {                                                                          \
    f16* bA_ = sm + ((T)&1) * 16384;                                            \
    gload16(aS1 + 64 * (T), bA_ + tid * 8);                                     \
    gload16(aS2 + 64 * (T), bA_ + 2048 + tid * 8);                              \
    gload16(aS1 + 64 * (T) + 32, bA_ + 4096 + tid * 8);                         \
    gload16(aS2 + 64 * (T) + 32, bA_ + 4096 + 2048 + tid * 8);                  \
  } while (0)

#define CVT_W(T, RG)                                                            \
  do {                                                                          \
    f16* bB_ = sm + ((T)&1) * 16384 + 8192 + ch * 4096;                         \
    f16* g_ = chunkBase + (size_t)(2 * (T) + ch) * 4096;                        \
    _Pragma("unroll") for (int i_ = 0; i_ < 4; ++i_) {                          \
      f16x8 h_;                                                                 \
      _Pragma("unroll") for (int j_ = 0; j_ < 8; ++j_) h_[j_] = (f16)RG[j_][i_]; \
      const int c_ = 4 * cg + i_;                                               \
      const int u_ = ((c_ >> 4) << 6) + (khi << 4) + (c_ & 15);                 \
      *(f16x8*)(bB_ + (size_t)(u_ ^ (cg >> 2)) * 8) = h_;                       \
      *(f16x8*)(g_ + (size_t)u_ * 8) = h_;                                      \
    }                                                                           \
  } while (0)

  auto compute2 = [&](int par) {
    const f16* base = sm + par * 16384;
#pragma unroll
    for (int cc = 0; cc < 2; ++cc) {
      const f16* Ab = base + cc * 4096;
      const f16* Bb = base + 8192 + cc * 4096;
      f16x8 af[4], bf[4];
#pragma unroll
      for (int fm = 0; fm < 4; ++fm) {
        const int row = 64 * wm + 16 * fm + lo;
        af[fm] = *(const f16x8*)(Ab + row * 32 + 8 * (hi ^ (row & 3)));
      }
#pragma unroll
      for (int fn = 0; fn < 4; ++fn) {
        const int uu = ((wn * 4 + fn) << 6) + (hi << 4) + lo;
        bf[fn] = *(const f16x8*)(Bb + (size_t)(uu ^ (wn * 4 + fn)) * 8);
      }
      WAITL0();
      __builtin_amdgcn_sched_barrier(0);
      __builtin_amdgcn_s_setprio(1);
#pragma unroll
      for (int fm = 0; fm < 4; ++fm)
#pragma unroll
        for (int fn = 0; fn < 4; ++fn)
          acc[fm][fn] = __builtin_amdgcn_mfma_f32_16x16x32_f16(af[fm], bf[fn], acc[fm][fn], 0, 0, 0);
      __builtin_amdgcn_s_setprio(0);
    }
  };

  ISSUE_R(0, rgA);
  ISSUE_R(1, rgB);
  ISSUE_G(0);
  __builtin_amdgcn_sched_barrier(0);
  WAITV(12);
  __builtin_amdgcn_sched_barrier(0);
  CVT_W(0, rgA);
  __builtin_amdgcn_sched_barrier(0);

  for (int tt = 0; tt < 7; ++tt) {
    const int t0 = 2 * tt;
    ISSUE_R(t0 + 2, rgA);
    ISSUE_G(t0 + 1);
    __builtin_amdgcn_sched_barrier(0);
    WAITV(20);
    __builtin_amdgcn_sched_barrier(0);
    CVT_W(t0 + 1, rgB);
    __builtin_amdgcn_sched_barrier(0);
    WAITV(20);
    WAITL0();
    SBAR();
    compute2(0);
    SBAR();
    ISSUE_R(t0 + 3, rgB);
    ISSUE_G(t0 + 2);
    __builtin_amdgcn_sched_barrier(0);
    WAITV(20);
    __builtin_amdgcn_sched_barrier(0);
    CVT_W(t0 + 2, rgA);
    __builtin_amdgcn_sched_barrier(0);
    WAITV(20);
    WAITL0();
    SBAR();
    compute2(1);
    SBAR();
  }
  ISSUE_G(15);
  __builtin_amdgcn_sched_barrier(0);
  WAITV(12);
  __builtin_amdgcn_sched_barrier(0);
  CVT_W(15, rgB);
  __builtin_amdgcn_sched_barrier(0);
  WAITV(12);
  WAITL0();
  SBAR();
  compute2(0);
  SBAR();
  WAITV(4);
  __builtin_amdgcn_sched_barrier(0);
  SBAR();
  compute2(1);

#undef ISSUE_R
#undef ISSUE_G
#undef CVT_W

  f16* P = Part + (size_t)ks * (GG * NN);
#pragma unroll
  for (int fm = 0; fm < 4; ++fm)
#pragma unroll
    for (int fn = 0; fn < 4; ++fn) {
      const int n = n0 + 64 * wn + 16 * fn + lo;
#pragma unroll
      for (int rr = 0; rr < 4; ++rr) {
        const int g = 64 * wm + 16 * fm + 4 * hi + rr;
        P[(size_t)g * NN + n] = (f16)acc[fm][fn][rr];
      }
    }
}

// ---------------- phases 3/5: tapF (proven R1 3-buffer schedule, verbatim) --------
__device__ __forceinline__ void ph_tap(int b, int tid, f16* sm, const f16* __restrict__ A,
                                       const f16* __restrict__ Bt, f16* __restrict__ Part) {
  const int w = tid >> 6, l = tid & 63, lo = l & 15, hi = l >> 4;
  const int wm = w >> 1, wn = w & 1;
  const int nbk = b & 63, ks = b >> 6;
  const int n0 = nbk * 128;
  const int k0 = ks * 1024;

  const int r1 = tid >> 2, r2 = 64 + (tid >> 2), q = tid & 3;
  const f16* aS1 = A + (size_t)r1 * NN + k0 + 8 * (q ^ (r1 & 3));
  const f16* aS2 = A + (size_t)r2 * NN + k0 + 8 * (q ^ (r2 & 3));
  const f16* bBlk = Bt + (size_t)(ks * 64 + nbk) * (32 * 4096);

#pragma unroll
  for (int p = 0; p < 2; ++p) {
    f16* buf = sm + p * 8192;
    gload16(aS1 + p * 32, buf + tid * 8);
    gload16(aS2 + p * 32, buf + 2048 + tid * 8);
    gload16(bBlk + p * 4096 + tid * 8, buf + 4096 + tid * 8);
    gload16(bBlk + p * 4096 + 2048 + tid * 8, buf + 6144 + tid * 8);
  }

  f32x4 acc[4][4] = {};

  auto compute = [&](int cur) {
    const f16* Ab = sm + cur * 8192;
    const f16* Bb = Ab + 4096;
    f16x8 af[4], bf[4];
#pragma unroll
    for (int fm = 0; fm < 4; ++fm) {
      const int row = 64 * wm + 16 * fm + lo;
      af[fm] = *(const f16x8*)(Ab + row * 32 + 8 * (hi ^ (row & 3)));
    }
#pragma unroll
    for (int fn = 0; fn < 4; ++fn)
      bf[fn] = *(const f16x8*)(Bb + (wn * 4 + fn) * 512 + hi * 128 + lo * 8);
    WAITL0();
    __builtin_amdgcn_sched_barrier(0);
    __builtin_amdgcn_s_setprio(1);
#pragma unroll
    for (int fm = 0; fm < 4; ++fm)
#pragma unroll
      for (int fn = 0; fn < 4; ++fn)
        acc[fm][fn] = __builtin_amdgcn_mfma_f32_16x16x32_f16(af[fm], bf[fn], acc[fm][fn], 0, 0, 0);
    __builtin_amdgcn_s_setprio(0);
  };

  int cur = 0, rot = 2;
  for (int t = 0; t < 30; ++t) {
    f16* buf = sm + rot * 8192;
    const int ko = (t + 2) * 32;
    gload16(aS1 + ko, buf + tid * 8);
    gload16(aS2 + ko, buf + 2048 + tid * 8);
    gload16(bBlk + (size_t)(t + 2) * 4096 + tid * 8, buf + 4096 + tid * 8);
    gload16(bBlk + (size_t)(t + 2) * 4096 + 2048 + tid * 8, buf + 6144 + tid * 8);
    __builtin_amdgcn_sched_barrier(0);
    WAITV(8);
    SBAR();
    compute(cur);
    SBAR();
    cur = (cur == 2) ? 0 : cur + 1;
    rot = (rot == 2) ? 0 : rot + 1;
  }
  WAITV(4);
  SBAR();
  compute(cur);
  SBAR();
  cur = (cur == 2) ? 0 : cur + 1;
  WAITV(0);
  SBAR();
  compute(cur);

  f16* P = Part + (size_t)ks * (GG * NN);
#pragma unroll
  for (int fm = 0; fm < 4; ++fm)
#pragma unroll
    for (int fn = 0; fn < 4; ++fn) {
      const int n = n0 + 64 * wn + 16 * fn + lo;
#pragma unroll
      for (int rr = 0; rr < 4; ++rr) {
        const int g = 64 * wm + 16 * fm + 4 * hi + rr;
        P[(size_t)g * NN + n] = (f16)acc[fm][fn][rr];
      }
    }
}

// ---------------- phases 2/4/6: combine (verbatim, remapped to 512x256) ----------
__device__ __forceinline__ void ph_comb(int b, int tid, const f16* __restrict__ Part,
                                        const f16* __restrict__ wzk, f16* __restrict__ tn) {
  const int idx = b * 256 + tid;
  const size_t off = (size_t)idx * 8;
  f16x8 wv = *(const f16x8*)(wzk + off);
  float s[8];
#pragma unroll
  for (int j = 0; j < 8; ++j) s[j] = (float)wv[j];
#pragma unroll
  for (int sp = 0; sp < NSPLIT; ++sp) {
    f16x8 p = __builtin_nontemporal_load((const f16x8*)(Part + (size_t)sp * (GG * NN) + off));
#pragma unroll
    for (int j = 0; j < 8; ++j) s[j] += (float)p[j];
  }
  f16x8 o;
#pragma unroll
  for (int j = 0; j < 8; ++j) o[j] = (f16)s[j];
  *(f16x8*)(tn + off) = o;
}

__device__ __forceinline__ void ph_combF(int b, int tid, const f16* __restrict__ Part,
                                         const f16* __restrict__ wz0, const float* __restrict__ bias,
                                         float* __restrict__ y) {
  const int idx = b * 256 + tid;
  const size_t off = (size_t)idx * 8;
  f16x8 wv = *(const f16x8*)(wz0 + off);
  float s[8];
#pragma unroll
  for (int j = 0; j < 8; ++j) s[j] = (float)wv[j];
#pragma unroll
  for (int sp = 0; sp < NSPLIT; ++sp) {
    f16x8 p = __builtin_nontemporal_load((const f16x8*)(Part + (size_t)sp * (GG * NN) + off));
#pragma unroll
    for (int j = 0; j < 8; ++j) s[j] += (float)p[j];
  }
  const float bb = bias[(int)(off >> 13)];
  f32x4 o0, o1;
#pragma unroll
  for (int j = 0; j < 4; ++j) { o0[j] = s[j] + bb; o1[j] = s[4 + j] + bb; }
  __builtin_nontemporal_store(o0, (f32x4*)(y + off));
  __builtin_nontemporal_store(o1, (f32x4*)(y + off + 4));
}

// ---------------- the single fused dispatch ----------------
__global__ __launch_bounds__(256, 2) void k_all(
    const float* __restrict__ wt, const float* __restrict__ x, const float* __restrict__ S,
    const float* __restrict__ bs, f16* __restrict__ Sbt, f16* __restrict__ wz,
    f16* __restrict__ ta, f16* __restrict__ tb, f16* __restrict__ Part,
    float* __restrict__ y, unsigned* __restrict__ cnt) {
  __shared__ __align__(16) f16 sm[2 * 16384];  // 64 KB -> exactly 2 blocks/CU
  const int b = (int)blockIdx.x, tid = (int)threadIdx.x;

  ph_wz(b, tid, wt, x, wz);
  gbar(cnt, 1 * 512);
  ph_tap1(b, tid, sm, wz + (size_t)3 * GG * NN, S, Sbt, Part);
  gbar(cnt, 2 * 512);
  ph_comb(b, tid, Part, wz + (size_t)2 * GG * NN, ta);
  gbar(cnt, 3 * 512);
  ph_tap(b, tid, sm, ta, Sbt, Part);
  gbar(cnt, 4 * 512);
  ph_comb(b, tid, Part, wz + (size_t)1 * GG * NN, tb);
  gbar(cnt, 5 * 512);
  ph_tap(b, tid, sm, tb, Sbt, Part);
  gbar(cnt, 6 * 512);
  ph_combF(b, tid, Part, wz, bs, y);
}

extern "C" void kernel_launch(void* const* d_in, const int* in_sizes, int n_in, void* d_out,
                              int out_size, void* d_ws, size_t ws_size, hipStream_t stream) {
  const float* x = (const float*)d_in[0];   // [8192][128]
  const float* S = (const float*)d_in[1];   // [8192][8192] fp32
  const float* wt = (const float*)d_in[2];  // [128][1][4][128]
  const float* bs = (const float*)d_in[3];  // [128]
  float* y = (float*)d_out;                 // [128][8192] fp32
  char* ws = (char*)d_ws;

  const size_t offSbt = 0;                               // Sbt tiled f16: 134.2 MB
  const size_t offWz = offSbt + (size_t)NN * NN * 2;     // wz[4][128][8192] f16: 8 MB
  const size_t offTa = offWz + (size_t)4 * GG * NN * 2;  // t buf A: 2 MB
  const size_t offTb = offTa + (size_t)GG * NN * 2;      // t buf B: 2 MB
  const size_t offP = offTb + (size_t)GG * NN * 2;       // Part f16 [8][128][8192]: 16.8 MB
  const size_t offCnt = offP + (size_t)NSPLIT * GG * NN * 2;
  const size_t need = offCnt + 256;
  if (ws_size < need) return;

  f16* Sbt = (f16*)(ws + offSbt);
  f16* wz = (f16*)(ws + offWz);
  f16* ta = (f16*)(ws + offTa);
  f16* tb = (f16*)(ws + offTb);
  f16* Part = (f16*)(ws + offP);
  unsigned* cnt = (unsigned*)(ws + offCnt);

  hipMemsetAsync(cnt, 0, 256, stream);
  k_all<<<dim3(512), 256, 0, stream>>>(wt, x, S, bs, Sbt, wz, ta, tb, Part, y, cnt);
}

// Round 6
// 178.191 us; speedup vs baseline: 3.9534x; 3.9534x over previous
//
#include <hip/hip_runtime.h>

typedef _Float16 f16;
typedef _Float16 f16x8 __attribute__((ext_vector_type(8)));
typedef float f32x4 __attribute__((ext_vector_type(4)));

#define NN 8192
#define GG 128
#define NSPLIT 8

typedef __attribute__((address_space(3))) unsigned as3u;
typedef const __attribute__((address_space(1))) unsigned as1u;

__device__ __forceinline__ void gload16(const f16* g, f16* l) {
  __builtin_amdgcn_global_load_lds((as1u*)g, (as3u*)l, 16, 0, 0);
}

#define SBAR() asm volatile("s_barrier" ::: "memory")
#define WAITV(N) asm volatile("s_waitcnt vmcnt(" #N ")" ::: "memory")
#define WAITL0() asm volatile("s_waitcnt lgkmcnt(0)" ::: "memory")

__device__ __forceinline__ f16x8 ldcvt8(const float* p) {
  f32x4 a = *(const f32x4*)p;
  f32x4 b = *(const f32x4*)(p + 4);
  f16x8 r;
  r[0] = (f16)a[0]; r[1] = (f16)a[1]; r[2] = (f16)a[2]; r[3] = (f16)a[3];
  r[4] = (f16)b[0]; r[5] = (f16)b[1]; r[6] = (f16)b[2]; r[7] = (f16)b[3];
  return r;
}

// ---------------- wz[k] = W_k @ z0 for k=0..3 (proven) ----------------
__global__ __launch_bounds__(512, 2) void k_wz(const float* __restrict__ wt,
                                               const float* __restrict__ x,
                                               f16* __restrict__ wz) {
  const int tid = (int)threadIdx.x;
  const int w = tid >> 6, l = tid & 63, lo = l & 15, hi = l >> 4;
  const int rg = w >> 1, cg = w & 1;
  const int ktap = (int)blockIdx.y;
  const int n0 = (int)blockIdx.x * 32;
  const int rowA = rg * 32;
  const float* wA0 = wt + (size_t)(rowA + lo) * 512 + (size_t)ktap * 128 + 8 * hi;
  const float* wA1 = wA0 + (size_t)16 * 512;
  const float* xB = x + (size_t)(n0 + 16 * cg + lo) * GG + 8 * hi;
  f32x4 acc[2] = {};
#pragma unroll
  for (int s = 0; s < 4; ++s) {
    f16x8 a0 = ldcvt8(wA0 + s * 32);
    f16x8 a1 = ldcvt8(wA1 + s * 32);
    f16x8 b = ldcvt8(xB + s * 32);
    acc[0] = __builtin_amdgcn_mfma_f32_16x16x32_f16(a0, b, acc[0], 0, 0, 0);
    acc[1] = __builtin_amdgcn_mfma_f32_16x16x32_f16(a1, b, acc[1], 0, 0, 0);
  }
  f16* out = wz + (size_t)ktap * (GG * NN);
#pragma unroll
  for (int fm = 0; fm < 2; ++fm)
#pragma unroll
    for (int rr = 0; rr < 4; ++rr) {
      int row = rowA + 16 * fm + 4 * hi + rr;
      out[(size_t)row * NN + n0 + 16 * cg + lo] = (f16)acc[fm][rr];
    }
}

// ---------------- fused tap1: stream S fp32 -> cvt f16 -> {LDS B (swz), Sbt} + MFMA ----
// Proven R2 schedule. Part stores now NONTEMPORAL (write-once-read-once stream;
// keep it from evicting the L3-resident Sbt that the two tapFs re-read).
__global__ __launch_bounds__(256, 2) void k_tap1F(const f16* __restrict__ A,
                                                  const float* __restrict__ S,
                                                  f16* __restrict__ Sbt,
                                                  f16* __restrict__ Part) {
  __shared__ __align__(16) f16 sm[2 * 16384];  // 2 bufs x (A 16KB + B 16KB)

  const int tid = (int)threadIdx.x;
  const int w = tid >> 6, l = tid & 63, lo = l & 15, hi = l >> 4;
  const int wm = w >> 1, wn = w & 1;
  const int kg = tid >> 5, cg = tid & 31, ch = kg >> 2, khi = kg & 3;
  const int nb = (int)blockIdx.x, ks = (int)blockIdx.y;
  const int n0 = nb * 128;
  const int k0 = ks * 1024;

  const int r1 = tid >> 2, q = tid & 3;
  const f16* aS1 = A + (size_t)r1 * NN + k0 + 8 * (q ^ (r1 & 3));
  const f16* aS2 = A + (size_t)(64 + r1) * NN + k0 + 8 * (q ^ (r1 & 3));
  const float* Sb = S + (size_t)(k0 + 8 * kg) * NN + n0 + 4 * cg;
  f16* chunkBase = Sbt + (((size_t)ks * 64 + nb) * 32) * 4096;  // 32 chunks of 4KB

  f32x4 rgA[8], rgB[8];
  f32x4 acc[4][4] = {};

#define ISSUE_R(T, RG)                                                          \
  do {                                                                          \
    const float* s_ = Sb + (size_t)(64 * (T)) * NN;                             \
    _Pragma("unroll") for (int j_ = 0; j_ < 8; ++j_)                            \
        RG[j_] = __builtin_nontemporal_load((const f32x4*)(s_ + (size_t)j_ * NN)); \
  } while (0)

#define ISSUE_G(T)                                                              \
  do {                                                                          \
    f16* bA_ = sm + ((T)&1) * 16384;                                            \
    gload16(aS1 + 64 * (T), bA_ + tid * 8);                                     \
    gload16(aS2 + 64 * (T), bA_ + 2048 + tid * 8);                              \
    gload16(aS1 + 64 * (T) + 32, bA_ + 4096 + tid * 8);                         \
    gload16(aS2 + 64 * (T) + 32, bA_ + 4096 + 2048 + tid * 8);                  \
  } while (0)

#define CVT_W(T, RG)                                                            \
  do {                                                                          \
    f16* bB_ = sm + ((T)&1) * 16384 + 8192 + ch * 4096;                         \
    f16* g_ = chunkBase + (size_t)(2 * (T) + ch) * 4096;                        \
    _Pragma("unroll") for (int i_ = 0; i_ < 4; ++i_) {                          \
      f16x8 h_;                                                                 \
      _Pragma("unroll") for (int j_ = 0; j_ < 8; ++j_) h_[j_] = (f16)RG[j_][i_]; \
      const int c_ = 4 * cg + i_;                                               \
      const int u_ = ((c_ >> 4) << 6) + (khi << 4) + (c_ & 15);                 \
      *(f16x8*)(bB_ + (size_t)(u_ ^ (cg >> 2)) * 8) = h_;                       \
      *(f16x8*)(g_ + (size_t)u_ * 8) = h_;                                      \
    }                                                                           \
  } while (0)

  auto compute2 = [&](int par) {  // one 64-k pair = 2 chunks x 16 MFMA
    const f16* base = sm + par * 16384;
#pragma unroll
    for (int cc = 0; cc < 2; ++cc) {
      const f16* Ab = base + cc * 4096;
      const f16* Bb = base + 8192 + cc * 4096;
      f16x8 af[4], bf[4];
#pragma unroll
      for (int fm = 0; fm < 4; ++fm) {
        const int row = 64 * wm + 16 * fm + lo;
        af[fm] = *(const f16x8*)(Ab + row * 32 + 8 * (hi ^ (row & 3)));
      }
#pragma unroll
      for (int fn = 0; fn < 4; ++fn) {
        const int uu = ((wn * 4 + fn) << 6) + (hi << 4) + lo;
        bf[fn] = *(const f16x8*)(Bb + (size_t)(uu ^ (wn * 4 + fn)) * 8);
      }
      WAITL0();
      __builtin_amdgcn_sched_barrier(0);
      __builtin_amdgcn_s_setprio(1);
#pragma unroll
      for (int fm = 0; fm < 4; ++fm)
#pragma unroll
        for (int fn = 0; fn < 4; ++fn)
          acc[fm][fn] = __builtin_amdgcn_mfma_f32_16x16x32_f16(af[fm], bf[fn], acc[fm][fn], 0, 0, 0);
      __builtin_amdgcn_s_setprio(0);
    }
  };

  ISSUE_R(0, rgA);
  ISSUE_R(1, rgB);
  ISSUE_G(0);
  __builtin_amdgcn_sched_barrier(0);
  WAITV(12);
  __builtin_amdgcn_sched_barrier(0);
  CVT_W(0, rgA);
  __builtin_amdgcn_sched_barrier(0);

  for (int tt = 0; tt < 7; ++tt) {
    const int t0 = 2 * tt;
    ISSUE_R(t0 + 2, rgA);
    ISSUE_G(t0 + 1);
    __builtin_amdgcn_sched_barrier(0);
    WAITV(20);  // R8(p t0+1) done: after it G4+S4+R8+G4 = 20
    __builtin_amdgcn_sched_barrier(0);
    CVT_W(t0 + 1, rgB);
    __builtin_amdgcn_sched_barrier(0);
    WAITV(20);  // G4(p t0) done: after it S4+R8+G4+S4 = 20
    WAITL0();
    SBAR();
    compute2(0);
    SBAR();
    ISSUE_R(t0 + 3, rgB);
    ISSUE_G(t0 + 2);
    __builtin_amdgcn_sched_barrier(0);
    WAITV(20);
    __builtin_amdgcn_sched_barrier(0);
    CVT_W(t0 + 2, rgA);
    __builtin_amdgcn_sched_barrier(0);
    WAITV(20);
    WAITL0();
    SBAR();
    compute2(1);
    SBAR();
  }
  ISSUE_G(15);
  __builtin_amdgcn_sched_barrier(0);
  WAITV(12);
  __builtin_amdgcn_sched_barrier(0);
  CVT_W(15, rgB);
  __builtin_amdgcn_sched_barrier(0);
  WAITV(12);
  WAITL0();
  SBAR();
  compute2(0);
  SBAR();
  WAITV(4);
  __builtin_amdgcn_sched_barrier(0);
  SBAR();
  compute2(1);

#undef ISSUE_R
#undef ISSUE_G
#undef CVT_W

  f16* P = Part + (size_t)blockIdx.y * (GG * NN);
#pragma unroll
  for (int fm = 0; fm < 4; ++fm)
#pragma unroll
    for (int fn = 0; fn < 4; ++fn) {
      const int n = n0 + 64 * wn + 16 * fn + lo;
#pragma unroll
      for (int rr = 0; rr < 4; ++rr) {
        const int g = 64 * wm + 16 * fm + 4 * hi + rr;
        __builtin_nontemporal_store((f16)acc[fm][fn][rr], &P[(size_t)g * NN + n]);
      }
    }
}

// ---------------- taps 2/3: proven R1 triple-buffer; NT Part stores ----------------
__global__ __launch_bounds__(256, 3) void k_tapF(const f16* __restrict__ A,
                                                 const f16* __restrict__ Bt,
                                                 f16* __restrict__ Part) {
  __shared__ __align__(16) f16 sm[3 * 8192];  // 3 x (A 8KB + B 8KB)

  const int tid = (int)threadIdx.x;
  const int w = tid >> 6, l = tid & 63, lo = l & 15, hi = l >> 4;
  const int wm = w >> 1, wn = w & 1;
  const int n0 = (int)blockIdx.x * 128;
  const int k0 = (int)blockIdx.y * 1024;  // NSPLIT=8 -> K=1024, 32 steps

  const int r1 = tid >> 2, r2 = 64 + (tid >> 2), q = tid & 3;
  const f16* aS1 = A + (size_t)r1 * NN + k0 + 8 * (q ^ (r1 & 3));
  const f16* aS2 = A + (size_t)r2 * NN + k0 + 8 * (q ^ (r2 & 3));
  const f16* bBlk = Bt + (size_t)((int)blockIdx.y * 64 + (int)blockIdx.x) * (32 * 4096);

#pragma unroll
  for (int p = 0; p < 2; ++p) {
    f16* buf = sm + p * 8192;
    gload16(aS1 + p * 32, buf + tid * 8);
    gload16(aS2 + p * 32, buf + 2048 + tid * 8);
    gload16(bBlk + p * 4096 + tid * 8, buf + 4096 + tid * 8);
    gload16(bBlk + p * 4096 + 2048 + tid * 8, buf + 6144 + tid * 8);
  }

  f32x4 acc[4][4] = {};

  auto compute = [&](int cur) {
    const f16* Ab = sm + cur * 8192;
    const f16* Bb = Ab + 4096;
    f16x8 af[4], bf[4];
#pragma unroll
    for (int fm = 0; fm < 4; ++fm) {
      const int row = 64 * wm + 16 * fm + lo;
      af[fm] = *(const f16x8*)(Ab + row * 32 + 8 * (hi ^ (row & 3)));
    }
#pragma unroll
    for (int fn = 0; fn < 4; ++fn)
      bf[fn] = *(const f16x8*)(Bb + (wn * 4 + fn) * 512 + hi * 128 + lo * 8);
    WAITL0();
    __builtin_amdgcn_sched_barrier(0);
    __builtin_amdgcn_s_setprio(1);
#pragma unroll
    for (int fm = 0; fm < 4; ++fm)
#pragma unroll
      for (int fn = 0; fn < 4; ++fn)
        acc[fm][fn] = __builtin_amdgcn_mfma_f32_16x16x32_f16(af[fm], bf[fn], acc[fm][fn], 0, 0, 0);
    __builtin_amdgcn_s_setprio(0);
  };

  int cur = 0, rot = 2;
  for (int t = 0; t < 30; ++t) {
    f16* buf = sm + rot * 8192;
    const int ko = (t + 2) * 32;
    gload16(aS1 + ko, buf + tid * 8);
    gload16(aS2 + ko, buf + 2048 + tid * 8);
    gload16(bBlk + (size_t)(t + 2) * 4096 + tid * 8, buf + 4096 + tid * 8);
    gload16(bBlk + (size_t)(t + 2) * 4096 + 2048 + tid * 8, buf + 6144 + tid * 8);
    __builtin_amdgcn_sched_barrier(0);
    WAITV(8);
    SBAR();
    compute(cur);
    SBAR();
    cur = (cur == 2) ? 0 : cur + 1;
    rot = (rot == 2) ? 0 : rot + 1;
  }
  WAITV(4);
  SBAR();
  compute(cur);
  SBAR();
  cur = (cur == 2) ? 0 : cur + 1;
  WAITV(0);
  SBAR();
  compute(cur);

  f16* P = Part + (size_t)blockIdx.y * (GG * NN);
#pragma unroll
  for (int fm = 0; fm < 4; ++fm)
#pragma unroll
    for (int fn = 0; fn < 4; ++fn) {
      const int n = n0 + 64 * wn + 16 * fn + lo;
#pragma unroll
      for (int rr = 0; rr < 4; ++rr) {
        const int g = 64 * wm + 16 * fm + 4 * hi + rr;
        __builtin_nontemporal_store((f16)acc[fm][fn][rr], &P[(size_t)g * NN + n]);
      }
    }
}

// ---------------- combine: vectorized 16-B loads, 8 elems/thread ----------------
template <int FINAL>
__global__ void k_combine(const f16* __restrict__ Part, const f16* __restrict__ wz,
                          const float* __restrict__ bias, f16* __restrict__ tn,
                          float* __restrict__ y) {
  const int idx = (int)blockIdx.x * 512 + (int)threadIdx.x;  // 8 elems each
  const size_t off = (size_t)idx * 8;
  f16x8 wv = *(const f16x8*)(wz + off);
  float s[8];
#pragma unroll
  for (int j = 0; j < 8; ++j) s[j] = (float)wv[j];
#pragma unroll
  for (int sp = 0; sp < NSPLIT; ++sp) {
    f16x8 p = __builtin_nontemporal_load((const f16x8*)(Part + (size_t)sp * (GG * NN) + off));
#pragma unroll
    for (int j = 0; j < 8; ++j) s[j] += (float)p[j];
  }
  if (FINAL) {
    const float b = bias[(int)(off >> 13)];
    f32x4 o0, o1;
#pragma unroll
    for (int j = 0; j < 4; ++j) { o0[j] = s[j] + b; o1[j] = s[4 + j] + b; }
    __builtin_nontemporal_store(o0, (f32x4*)(y + off));
    __builtin_nontemporal_store(o1, (f32x4*)(y + off + 4));
  } else {
    f16x8 o;
#pragma unroll
    for (int j = 0; j < 8; ++j) o[j] = (f16)s[j];
    *(f16x8*)(tn + off) = o;
  }
}

extern "C" void kernel_launch(void* const* d_in, const int* in_sizes, int n_in, void* d_out,
                              int out_size, void* d_ws, size_t ws_size, hipStream_t stream) {
  const float* x = (const float*)d_in[0];   // [8192][128]
  const float* S = (const float*)d_in[1];   // [8192][8192] fp32
  const float* wt = (const float*)d_in[2];  // [128][1][4][128]
  const float* bs = (const float*)d_in[3];  // [128]
  float* y = (float*)d_out;                 // [128][8192] fp32
  char* ws = (char*)d_ws;

  const size_t offSbt = 0;                               // Sbt tiled f16: 134.2 MB
  const size_t offWz = offSbt + (size_t)NN * NN * 2;     // wz[4][128][8192] f16: 8 MB
  const size_t offTa = offWz + (size_t)4 * GG * NN * 2;  // t buf A: 2 MB
  const size_t offTb = offTa + (size_t)GG * NN * 2;      // t buf B: 2 MB
  const size_t offP = offTb + (size_t)GG * NN * 2;       // Part f16 [8][128][8192]: 16.8 MB
  const size_t need = offP + (size_t)NSPLIT * GG * NN * 2;
  if (ws_size < need) return;

  f16* Sbt = (f16*)(ws + offSbt);
  f16* wz = (f16*)(ws + offWz);
  f16* ta = (f16*)(ws + offTa);
  f16* tb = (f16*)(ws + offTb);
  f16* Part = (f16*)(ws + offP);

  // wz first (tap1 consumes wz3), then fused stream+tap1, then Horner chain.
  k_wz<<<dim3(256, 4), 512, 0, stream>>>(wt, x, wz);
  k_tap1F<<<dim3(64, NSPLIT), 256, 0, stream>>>(wz + (size_t)3 * GG * NN, S, Sbt, Part);
  k_combine<0><<<dim3(256), 512, 0, stream>>>(Part, wz + (size_t)2 * GG * NN, nullptr, ta, nullptr);
  k_tapF<<<dim3(64, NSPLIT), 256, 0, stream>>>(ta, Sbt, Part);
  k_combine<0><<<dim3(256), 512, 0, stream>>>(Part, wz + (size_t)1 * GG * NN, nullptr, tb, nullptr);
  k_tapF<<<dim3(64, NSPLIT), 256, 0, stream>>>(tb, Sbt, Part);
  k_combine<1><<<dim3(256), 512, 0, stream>>>(Part, wz, bs, nullptr, y);
}

// Round 7
// 171.320 us; speedup vs baseline: 4.1119x; 1.0401x over previous
//
#include <hip/hip_runtime.h>

typedef _Float16 f16;
typedef _Float16 f16x8 __attribute__((ext_vector_type(8)));
typedef float f32x4 __attribute__((ext_vector_type(4)));

#define NN 8192
#define GG 128
#define NSPLIT 8

typedef __attribute__((address_space(3))) unsigned as3u;
typedef const __attribute__((address_space(1))) unsigned as1u;

__device__ __forceinline__ void gload16(const f16* g, f16* l) {
  __builtin_amdgcn_global_load_lds((as1u*)g, (as3u*)l, 16, 0, 0);
}

#define SBAR() asm volatile("s_barrier" ::: "memory")
#define WAITV(N) asm volatile("s_waitcnt vmcnt(" #N ")" ::: "memory")
#define WAITL0() asm volatile("s_waitcnt lgkmcnt(0)" ::: "memory")

__device__ __forceinline__ f16x8 ldcvt8(const float* p) {
  f32x4 a = *(const f32x4*)p;
  f32x4 b = *(const f32x4*)(p + 4);
  f16x8 r;
  r[0] = (f16)a[0]; r[1] = (f16)a[1]; r[2] = (f16)a[2]; r[3] = (f16)a[3];
  r[4] = (f16)b[0]; r[5] = (f16)b[1]; r[6] = (f16)b[2]; r[7] = (f16)b[3];
  return r;
}

// ---------------- wz[k] = W_k @ z0 for k=0..3 (proven) ----------------
__global__ __launch_bounds__(512, 2) void k_wz(const float* __restrict__ wt,
                                               const float* __restrict__ x,
                                               f16* __restrict__ wz) {
  const int tid = (int)threadIdx.x;
  const int w = tid >> 6, l = tid & 63, lo = l & 15, hi = l >> 4;
  const int rg = w >> 1, cg = w & 1;
  const int ktap = (int)blockIdx.y;
  const int n0 = (int)blockIdx.x * 32;
  const int rowA = rg * 32;
  const float* wA0 = wt + (size_t)(rowA + lo) * 512 + (size_t)ktap * 128 + 8 * hi;
  const float* wA1 = wA0 + (size_t)16 * 512;
  const float* xB = x + (size_t)(n0 + 16 * cg + lo) * GG + 8 * hi;
  f32x4 acc[2] = {};
#pragma unroll
  for (int s = 0; s < 4; ++s) {
    f16x8 a0 = ldcvt8(wA0 + s * 32);
    f16x8 a1 = ldcvt8(wA1 + s * 32);
    f16x8 b = ldcvt8(xB + s * 32);
    acc[0] = __builtin_amdgcn_mfma_f32_16x16x32_f16(a0, b, acc[0], 0, 0, 0);
    acc[1] = __builtin_amdgcn_mfma_f32_16x16x32_f16(a1, b, acc[1], 0, 0, 0);
  }
  f16* out = wz + (size_t)ktap * (GG * NN);
#pragma unroll
  for (int fm = 0; fm < 2; ++fm)
#pragma unroll
    for (int rr = 0; rr < 4; ++rr) {
      int row = rowA + 16 * fm + 4 * hi + rr;
      out[(size_t)row * NN + n0 + 16 * cg + lo] = (f16)acc[fm][rr];
    }
}

// ---------------- fused tap1: stream S fp32 -> cvt f16 -> {LDS B (swz), Sbt} + MFMA ----
// Proven R2 schedule verbatim. Part stores plain (cached): R6 proved NT Part
// stores regress -7us (L2 write-coalescing + near-term combine re-reads matter).
__global__ __launch_bounds__(256, 2) void k_tap1F(const f16* __restrict__ A,
                                                  const float* __restrict__ S,
                                                  f16* __restrict__ Sbt,
                                                  f16* __restrict__ Part) {
  __shared__ __align__(16) f16 sm[2 * 16384];  // 2 bufs x (A 16KB + B 16KB)

  const int tid = (int)threadIdx.x;
  const int w = tid >> 6, l = tid & 63, lo = l & 15, hi = l >> 4;
  const int wm = w >> 1, wn = w & 1;
  const int kg = tid >> 5, cg = tid & 31, ch = kg >> 2, khi = kg & 3;
  const int nb = (int)blockIdx.x, ks = (int)blockIdx.y;
  const int n0 = nb * 128;
  const int k0 = ks * 1024;

  const int r1 = tid >> 2, q = tid & 3;
  const f16* aS1 = A + (size_t)r1 * NN + k0 + 8 * (q ^ (r1 & 3));
  const f16* aS2 = A + (size_t)(64 + r1) * NN + k0 + 8 * (q ^ (r1 & 3));
  const float* Sb = S + (size_t)(k0 + 8 * kg) * NN + n0 + 4 * cg;
  f16* chunkBase = Sbt + (((size_t)ks * 64 + nb) * 32) * 4096;  // 32 chunks of 4KB

  f32x4 rgA[8], rgB[8];
  f32x4 acc[4][4] = {};

#define ISSUE_R(T, RG)                                                          \
  do {                                                                          \
    const float* s_ = Sb + (size_t)(64 * (T)) * NN;                             \
    _Pragma("unroll") for (int j_ = 0; j_ < 8; ++j_)                            \
        RG[j_] = __builtin_nontemporal_load((const f32x4*)(s_ + (size_t)j_ * NN)); \
  } while (0)

#define ISSUE_G(T)                                                              \
  do {                                                                          \
    f16* bA_ = sm + ((T)&1) * 16384;                                            \
    gload16(aS1 + 64 * (T), bA_ + tid * 8);                                     \
    gload16(aS2 + 64 * (T), bA_ + 2048 + tid * 8);                              \
    gload16(aS1 + 64 * (T) + 32, bA_ + 4096 + tid * 8);                         \
    gload16(aS2 + 64 * (T) + 32, bA_ + 4096 + 2048 + tid * 8);                  \
  } while (0)

#define CVT_W(T, RG)                                                            \
  do {                                                                          \
    f16* bB_ = sm + ((T)&1) * 16384 + 8192 + ch * 4096;                         \
    f16* g_ = chunkBase + (size_t)(2 * (T) + ch) * 4096;                        \
    _Pragma("unroll") for (int i_ = 0; i_ < 4; ++i_) {                          \
      f16x8 h_;                                                                 \
      _Pragma("unroll") for (int j_ = 0; j_ < 8; ++j_) h_[j_] = (f16)RG[j_][i_]; \
      const int c_ = 4 * cg + i_;                                               \
      const int u_ = ((c_ >> 4) << 6) + (khi << 4) + (c_ & 15);                 \
      *(f16x8*)(bB_ + (size_t)(u_ ^ (cg >> 2)) * 8) = h_;                       \
      *(f16x8*)(g_ + (size_t)u_ * 8) = h_;                                      \
    }                                                                           \
  } while (0)

  auto compute2 = [&](int par) {  // one 64-k pair = 2 chunks x 16 MFMA
    const f16* base = sm + par * 16384;
#pragma unroll
    for (int cc = 0; cc < 2; ++cc) {
      const f16* Ab = base + cc * 4096;
      const f16* Bb = base + 8192 + cc * 4096;
      f16x8 af[4], bf[4];
#pragma unroll
      for (int fm = 0; fm < 4; ++fm) {
        const int row = 64 * wm + 16 * fm + lo;
        af[fm] = *(const f16x8*)(Ab + row * 32 + 8 * (hi ^ (row & 3)));
      }
#pragma unroll
      for (int fn = 0; fn < 4; ++fn) {
        const int uu = ((wn * 4 + fn) << 6) + (hi << 4) + lo;
        bf[fn] = *(const f16x8*)(Bb + (size_t)(uu ^ (wn * 4 + fn)) * 8);
      }
      WAITL0();
      __builtin_amdgcn_sched_barrier(0);
      __builtin_amdgcn_s_setprio(1);
#pragma unroll
      for (int fm = 0; fm < 4; ++fm)
#pragma unroll
        for (int fn = 0; fn < 4; ++fn)
          acc[fm][fn] = __builtin_amdgcn_mfma_f32_16x16x32_f16(af[fm], bf[fn], acc[fm][fn], 0, 0, 0);
      __builtin_amdgcn_s_setprio(0);
    }
  };

  ISSUE_R(0, rgA);
  ISSUE_R(1, rgB);
  ISSUE_G(0);
  __builtin_amdgcn_sched_barrier(0);
  WAITV(12);
  __builtin_amdgcn_sched_barrier(0);
  CVT_W(0, rgA);
  __builtin_amdgcn_sched_barrier(0);

  for (int tt = 0; tt < 7; ++tt) {
    const int t0 = 2 * tt;
    ISSUE_R(t0 + 2, rgA);
    ISSUE_G(t0 + 1);
    __builtin_amdgcn_sched_barrier(0);
    WAITV(20);  // R8(p t0+1) done: after it G4+S4+R8+G4 = 20
    __builtin_amdgcn_sched_barrier(0);
    CVT_W(t0 + 1, rgB);
    __builtin_amdgcn_sched_barrier(0);
    WAITV(20);  // G4(p t0) done: after it S4+R8+G4+S4 = 20
    WAITL0();
    SBAR();
    compute2(0);
    SBAR();
    ISSUE_R(t0 + 3, rgB);
    ISSUE_G(t0 + 2);
    __builtin_amdgcn_sched_barrier(0);
    WAITV(20);
    __builtin_amdgcn_sched_barrier(0);
    CVT_W(t0 + 2, rgA);
    __builtin_amdgcn_sched_barrier(0);
    WAITV(20);
    WAITL0();
    SBAR();
    compute2(1);
    SBAR();
  }
  ISSUE_G(15);
  __builtin_amdgcn_sched_barrier(0);
  WAITV(12);
  __builtin_amdgcn_sched_barrier(0);
  CVT_W(15, rgB);
  __builtin_amdgcn_sched_barrier(0);
  WAITV(12);
  WAITL0();
  SBAR();
  compute2(0);
  SBAR();
  WAITV(4);
  __builtin_amdgcn_sched_barrier(0);
  SBAR();
  compute2(1);

#undef ISSUE_R
#undef ISSUE_G
#undef CVT_W

  f16* P = Part + (size_t)blockIdx.y * (GG * NN);
#pragma unroll
  for (int fm = 0; fm < 4; ++fm)
#pragma unroll
    for (int fn = 0; fn < 4; ++fn) {
      const int n = n0 + 64 * wn + 16 * fn + lo;
#pragma unroll
      for (int rr = 0; rr < 4; ++rr) {
        const int g = 64 * wm + 16 * fm + 4 * hi + rr;
        P[(size_t)g * NN + n] = (f16)acc[fm][fn][rr];
      }
    }
}

// ---------------- taps 2/3: depth-3 prefetch (4 bufs, 64 KB LDS), R2 verbatim ----
__global__ __launch_bounds__(256, 2) void k_tapF(const f16* __restrict__ A,
                                                 const f16* __restrict__ Bt,
                                                 f16* __restrict__ Part) {
  __shared__ __align__(16) f16 sm[4 * 8192];  // 4 x (A 8KB + B 8KB)

  const int tid = (int)threadIdx.x;
  const int w = tid >> 6, l = tid & 63, lo = l & 15, hi = l >> 4;
  const int wm = w >> 1, wn = w & 1;
  const int n0 = (int)blockIdx.x * 128;
  const int k0 = (int)blockIdx.y * 1024;  // NSPLIT=8 -> K=1024, 32 steps

  const int r1 = tid >> 2, r2 = 64 + (tid >> 2), q = tid & 3;
  const f16* aS1 = A + (size_t)r1 * NN + k0 + 8 * (q ^ (r1 & 3));
  const f16* aS2 = A + (size_t)r2 * NN + k0 + 8 * (q ^ (r2 & 3));
  const f16* bBlk = Bt + (size_t)((int)blockIdx.y * 64 + (int)blockIdx.x) * (32 * 4096);

#pragma unroll
  for (int p = 0; p < 3; ++p) {
    f16* buf = sm + p * 8192;
    gload16(aS1 + p * 32, buf + tid * 8);
    gload16(aS2 + p * 32, buf + 2048 + tid * 8);
    gload16(bBlk + p * 4096 + tid * 8, buf + 4096 + tid * 8);
    gload16(bBlk + p * 4096 + 2048 + tid * 8, buf + 6144 + tid * 8);
  }

  f32x4 acc[4][4] = {};

  auto compute = [&](int cur) {
    const f16* Ab = sm + cur * 8192;
    const f16* Bb = Ab + 4096;
    f16x8 af[4], bf[4];
#pragma unroll
    for (int fm = 0; fm < 4; ++fm) {
      const int row = 64 * wm + 16 * fm + lo;
      af[fm] = *(const f16x8*)(Ab + row * 32 + 8 * (hi ^ (row & 3)));
    }
#pragma unroll
    for (int fn = 0; fn < 4; ++fn)
      bf[fn] = *(const f16x8*)(Bb + (wn * 4 + fn) * 512 + hi * 128 + lo * 8);
    WAITL0();
    __builtin_amdgcn_sched_barrier(0);
    __builtin_amdgcn_s_setprio(1);
#pragma unroll
    for (int fm = 0; fm < 4; ++fm)
#pragma unroll
      for (int fn = 0; fn < 4; ++fn)
        acc[fm][fn] = __builtin_amdgcn_mfma_f32_16x16x32_f16(af[fm], bf[fn], acc[fm][fn], 0, 0, 0);
    __builtin_amdgcn_s_setprio(0);
  };

  // steady state: issue step t+3, wait step t (16 outstanding -> 12), compute t
  for (int t = 0; t < 29; ++t) {
    f16* buf = sm + ((t + 3) & 3) * 8192;
    const int ko = (t + 3) * 32;
    gload16(aS1 + ko, buf + tid * 8);
    gload16(aS2 + ko, buf + 2048 + tid * 8);
    gload16(bBlk + (size_t)(t + 3) * 4096 + tid * 8, buf + 4096 + tid * 8);
    gload16(bBlk + (size_t)(t + 3) * 4096 + 2048 + tid * 8, buf + 6144 + tid * 8);
    __builtin_amdgcn_sched_barrier(0);
    WAITV(12);
    SBAR();
    compute(t & 3);
    SBAR();
  }
  // tail: outstanding = steps 29,30,31 (12 loads)
  WAITV(8);
  SBAR();
  compute(29 & 3);
  SBAR();
  WAITV(4);
  SBAR();
  compute(30 & 3);
  SBAR();
  WAITV(0);
  SBAR();
  compute(31 & 3);

  f16* P = Part + (size_t)blockIdx.y * (GG * NN);
#pragma unroll
  for (int fm = 0; fm < 4; ++fm)
#pragma unroll
    for (int fn = 0; fn < 4; ++fn) {
      const int n = n0 + 64 * wn + 16 * fn + lo;
#pragma unroll
      for (int rr = 0; rr < 4; ++rr) {
        const int g = 64 * wm + 16 * fm + 4 * hi + rr;
        P[(size_t)g * NN + n] = (f16)acc[fm][fn][rr];
      }
    }
}

// ---------------- combine: vectorized 16-B loads, 8 elems/thread ----------------
template <int FINAL>
__global__ void k_combine(const f16* __restrict__ Part, const f16* __restrict__ wz,
                          const float* __restrict__ bias, f16* __restrict__ tn,
                          float* __restrict__ y) {
  const int idx = (int)blockIdx.x * 512 + (int)threadIdx.x;  // 8 elems each
  const size_t off = (size_t)idx * 8;
  f16x8 wv = *(const f16x8*)(wz + off);
  float s[8];
#pragma unroll
  for (int j = 0; j < 8; ++j) s[j] = (float)wv[j];
#pragma unroll
  for (int sp = 0; sp < NSPLIT; ++sp) {
    f16x8 p = __builtin_nontemporal_load((const f16x8*)(Part + (size_t)sp * (GG * NN) + off));
#pragma unroll
    for (int j = 0; j < 8; ++j) s[j] += (float)p[j];
  }
  if (FINAL) {
    const float b = bias[(int)(off >> 13)];
    f32x4 o0, o1;
#pragma unroll
    for (int j = 0; j < 4; ++j) { o0[j] = s[j] + b; o1[j] = s[4 + j] + b; }
    __builtin_nontemporal_store(o0, (f32x4*)(y + off));
    __builtin_nontemporal_store(o1, (f32x4*)(y + off + 4));
  } else {
    f16x8 o;
#pragma unroll
    for (int j = 0; j < 8; ++j) o[j] = (f16)s[j];
    *(f16x8*)(tn + off) = o;
  }
}

extern "C" void kernel_launch(void* const* d_in, const int* in_sizes, int n_in, void* d_out,
                              int out_size, void* d_ws, size_t ws_size, hipStream_t stream) {
  const float* x = (const float*)d_in[0];   // [8192][128]
  const float* S = (const float*)d_in[1];   // [8192][8192] fp32
  const float* wt = (const float*)d_in[2];  // [128][1][4][128]
  const float* bs = (const float*)d_in[3];  // [128]
  float* y = (float*)d_out;                 // [128][8192] fp32
  char* ws = (char*)d_ws;

  const size_t offSbt = 0;                               // Sbt tiled f16: 134.2 MB
  const size_t offWz = offSbt + (size_t)NN * NN * 2;     // wz[4][128][8192] f16: 8 MB
  const size_t offTa = offWz + (size_t)4 * GG * NN * 2;  // t buf A: 2 MB
  const size_t offTb = offTa + (size_t)GG * NN * 2;      // t buf B: 2 MB
  const size_t offP = offTb + (size_t)GG * NN * 2;       // Part f16 [8][128][8192]: 16.8 MB
  const size_t need = offP + (size_t)NSPLIT * GG * NN * 2;
  if (ws_size < need) return;

  f16* Sbt = (f16*)(ws + offSbt);
  f16* wz = (f16*)(ws + offWz);
  f16* ta = (f16*)(ws + offTa);
  f16* tb = (f16*)(ws + offTb);
  f16* Part = (f16*)(ws + offP);

  // wz first (tap1 consumes wz3), then fused stream+tap1, then Horner chain.
  k_wz<<<dim3(256, 4), 512, 0, stream>>>(wt, x, wz);
  k_tap1F<<<dim3(64, NSPLIT), 256, 0, stream>>>(wz + (size_t)3 * GG * NN, S, Sbt, Part);
  k_combine<0><<<dim3(256), 512, 0, stream>>>(Part, wz + (size_t)2 * GG * NN, nullptr, ta, nullptr);
  k_tapF<<<dim3(64, NSPLIT), 256, 0, stream>>>(ta, Sbt, Part);
  k_combine<0><<<dim3(256), 512, 0, stream>>>(Part, wz + (size_t)1 * GG * NN, nullptr, tb, nullptr);
  k_tapF<<<dim3(64, NSPLIT), 256, 0, stream>>>(tb, Sbt, Part);
  k_combine<1><<<dim3(256), 512, 0, stream>>>(Part, wz, bs, nullptr, y);
}